// Round 1
// baseline (173.262 us; speedup 1.0000x reference)
//
#include <hip/hip_runtime.h>
#include <cstdint>
#include <cstddef>

// Problem shape (fixed by setup_inputs): hidden [4,2048,2048] -> M=8192, K=2048, N=2048
#define MDIM 8192
#define NDIM 2048
#define KDIM 2048

constexpr int BM = 128, BN = 128, BK = 64;   // i8 tile: one 16x16x64 MFMA K-step per iter

typedef int v4i __attribute__((ext_vector_type(4)));

// ---------- async global->LDS (16B/lane, wave-uniform LDS base + lane*16) ----------
__device__ __forceinline__ void async_ld16(const void* g, void* l) {
    __builtin_amdgcn_global_load_lds(
        (const __attribute__((address_space(1))) int*)g,
        (__attribute__((address_space(3))) int*)l,
        16, 0, 0);
}

// ---------- quantize hidden_states: fp32 -> int8, q = clip(rint(x/s), -127, 127) ----------
__device__ __forceinline__ int q8(float x, float s) {
    float q = fminf(fmaxf(rintf(x / s), -127.f), 127.f);
    return ((int)q) & 0xff;
}

__global__ void quant_x_kernel(const float* __restrict__ x, uint32_t* __restrict__ xq,
                               const float* __restrict__ scale_p) {
    int i = blockIdx.x * blockDim.x + threadIdx.x;   // one float4 -> 4 bytes
    float s = fmaxf(scale_p[0], 1e-8f);
    float4 v = reinterpret_cast<const float4*>(x)[i];
    uint32_t p = (uint32_t)q8(v.x, s)
               | ((uint32_t)q8(v.y, s) << 8)
               | ((uint32_t)q8(v.z, s) << 16)
               | ((uint32_t)q8(v.w, s) << 24);
    xq[i] = p;
}

// ---------- quantize + transpose W: fp32 [K][N] -> int8 [N][K] ----------
__global__ void quant_wt_kernel(const float* __restrict__ w, int8_t* __restrict__ wt) {
    __shared__ int8_t t[64][65];           // t[c][r] = (int8)w[k0+r][n0+c]
    const int k0 = blockIdx.y * 64;
    const int n0 = blockIdx.x * 64;
    const int tid = threadIdx.x;           // 256 threads
    const int rr = tid >> 4;               // 0..15
    const int c4 = (tid & 15) * 4;         // 0..60
    for (int p = 0; p < 4; ++p) {
        int r = rr + p * 16;
        float4 v = *(const float4*)&w[(size_t)(k0 + r) * NDIM + n0 + c4];
        t[c4 + 0][r] = (int8_t)rintf(v.x);
        t[c4 + 1][r] = (int8_t)rintf(v.y);
        t[c4 + 2][r] = (int8_t)rintf(v.z);
        t[c4 + 3][r] = (int8_t)rintf(v.w);
    }
    __syncthreads();
    for (int p = 0; p < 4; ++p) {
        int c = rr + p * 16;
        uint32_t o = (uint32_t)(uint8_t)t[c][c4 + 0]
                   | ((uint32_t)(uint8_t)t[c][c4 + 1] << 8)
                   | ((uint32_t)(uint8_t)t[c][c4 + 2] << 16)
                   | ((uint32_t)(uint8_t)t[c][c4 + 3] << 24);
        *(uint32_t*)&wt[(size_t)(n0 + c) * KDIM + k0 + c4] = o;
    }
}

// ---------- i8 GEMM: C[M][N] = A[M][K] * Bt[N][K]^T + bias, int32 accum ----------
__global__ __launch_bounds__(256, 2)
void gemm_i8_kernel(const int8_t* __restrict__ A,   // [M][K] int8 (x_q)
                    const int8_t* __restrict__ Bt,  // [N][K] int8 (W^T)
                    const float* __restrict__ bias, // [N]
                    float* __restrict__ C) {        // [M][N] fp32
    __shared__ alignas(16) int8_t lA[BM * BK];  // 8 KB, row-major [m][kk], 64B rows
    __shared__ alignas(16) int8_t lB[BN * BK];  // 8 KB, row-major [n][kk]

    const int tid  = threadIdx.x;
    const int lane = tid & 63;
    const int wave = tid >> 6;           // 0..3
    const int wm   = wave & 1;           // wave row (0..1)  -> 64 rows
    const int wn   = wave >> 1;          // wave col (0..1)  -> 64 cols
    const int m0   = blockIdx.y * BM;
    const int n0   = blockIdx.x * BN;

    // --- staging addresses: wave covers bytes [wave*2048, +2048) of each 8KB tile,
    //     2 issues of 64 lanes * 16B = 1024B. LDS off o -> row o/64, kk o%64.
    const int r0 = wave * 32 + (lane >> 2);     // rows for issue 0
    const int r1 = r0 + 16;                     // rows for issue 1
    const int kk = (lane & 3) * 16;
    const int8_t* gA0 = A  + (size_t)(m0 + r0) * KDIM + kk;
    const int8_t* gA1 = A  + (size_t)(m0 + r1) * KDIM + kk;
    const int8_t* gB0 = Bt + (size_t)(n0 + r0) * KDIM + kk;
    const int8_t* gB1 = Bt + (size_t)(n0 + r1) * KDIM + kk;
    int8_t* ldsA0 = &lA[wave * 2048];
    int8_t* ldsA1 = &lA[wave * 2048 + 1024];
    int8_t* ldsB0 = &lB[wave * 2048];
    int8_t* ldsB1 = &lB[wave * 2048 + 1024];

    // --- fragment read offsets (A: lane holds A[m=lane&15][k=quad*16+j], j=0..15)
    const int quad = lane >> 4;
    const int lr   = lane & 15;
    const int aoff = (wm * 64 + lr) * BK + quad * 16;
    const int boff = (wn * 64 + lr) * BK + quad * 16;

    v4i acc[4][4];
    for (int i = 0; i < 4; ++i)
        for (int j = 0; j < 4; ++j)
            acc[i][j] = (v4i){0, 0, 0, 0};

    for (int k0 = 0; k0 < KDIM; k0 += BK) {
        __syncthreads();                       // all waves done reading previous tile
        async_ld16(gA0, ldsA0);
        async_ld16(gA1, ldsA1);
        async_ld16(gB0, ldsB0);
        async_ld16(gB1, ldsB1);
        gA0 += BK; gA1 += BK; gB0 += BK; gB1 += BK;
        __syncthreads();                       // drains vmcnt -> staged data visible

        v4i af[4], bf[4];
        for (int i = 0; i < 4; ++i)
            af[i] = *(const v4i*)&lA[aoff + i * 16 * BK];
        for (int j = 0; j < 4; ++j)
            bf[j] = *(const v4i*)&lB[boff + j * 16 * BK];
        for (int i = 0; i < 4; ++i)
            for (int j = 0; j < 4; ++j)
                acc[i][j] = __builtin_amdgcn_mfma_i32_16x16x64_i8(af[i], bf[j], acc[i][j], 0, 0, 0);
    }

    // --- epilogue: C/D layout col = lane&15, row = quad*4 + reg (verified, dtype-indep)
    const int crow = m0 + wm * 64 + quad * 4;
    const int ccol = n0 + wn * 64 + lr;
    float bj[4];
    for (int j = 0; j < 4; ++j) bj[j] = bias[ccol + j * 16];
    for (int i = 0; i < 4; ++i) {
        for (int j = 0; j < 4; ++j) {
            for (int r = 0; r < 4; ++r) {
                int row = crow + i * 16 + r;
                int col = ccol + j * 16;
                C[(size_t)row * NDIM + col] = (float)acc[i][j][r] + bj[j];
            }
        }
    }
}

extern "C" void kernel_launch(void* const* d_in, const int* in_sizes, int n_in,
                              void* d_out, int out_size, void* d_ws, size_t ws_size,
                              hipStream_t stream) {
    const float* x    = (const float*)d_in[0];   // [8192, 2048] fp32
    const float* w    = (const float*)d_in[1];   // [2048, 2048] fp32 (integer-valued)
    const float* xs   = (const float*)d_in[2];   // scalar
    const float* bias = (const float*)d_in[3];   // [2048]
    float* out = (float*)d_out;                  // [8192, 2048] fp32

    int8_t* xq = (int8_t*)d_ws;                          // 16 MB
    int8_t* wt = xq + (size_t)MDIM * KDIM;               //  4 MB

    quant_x_kernel<<<(MDIM * (KDIM / 4)) / 256, 256, 0, stream>>>(x, (uint32_t*)xq, xs);
    quant_wt_kernel<<<dim3(NDIM / 64, KDIM / 64), 256, 0, stream>>>(w, wt);
    gemm_i8_kernel<<<dim3(NDIM / BN, MDIM / BM), 256, 0, stream>>>(xq, wt, bias, out);
}

// Round 2
// 168.677 us; speedup vs baseline: 1.0272x; 1.0272x over previous
//
#include <hip/hip_runtime.h>
#include <cstdint>
#include <cstddef>

// Problem shape (fixed by setup_inputs): hidden [4,2048,2048] -> M=8192, K=2048, N=2048
#define MDIM 8192
#define NDIM 2048
#define KDIM 2048

constexpr int BM = 128, BN = 128, BK = 128;   // 2 MFMA K-steps per stage

typedef int v4i __attribute__((ext_vector_type(4)));

__device__ __forceinline__ void async_ld16(const void* g, void* l) {
    __builtin_amdgcn_global_load_lds(
        (const __attribute__((address_space(1))) int*)g,
        (__attribute__((address_space(3))) int*)l,
        16, 0, 0);
}

// ---------- quantize x: fp32 -> int8 via reciprocal-mul; 64B in / 16B out per thread ----------
__device__ __forceinline__ uint32_t q8(float x, float inv) {
    float q = fminf(fmaxf(rintf(x * inv), -127.f), 127.f);
    return (uint32_t)((int)q) & 0xffu;
}

__global__ void quant_x_kernel(const float4* __restrict__ x, uint4* __restrict__ xq,
                               const float* __restrict__ scale_p) {
    int t = blockIdx.x * blockDim.x + threadIdx.x;   // one uint4 (16 int8) per thread
    float inv = 1.0f / fmaxf(scale_p[0], 1e-8f);
    uint32_t w[4];
#pragma unroll
    for (int j = 0; j < 4; ++j) {
        float4 v = x[t * 4 + j];
        w[j] = q8(v.x, inv) | (q8(v.y, inv) << 8) | (q8(v.z, inv) << 16) | (q8(v.w, inv) << 24);
    }
    xq[t] = make_uint4(w[0], w[1], w[2], w[3]);
}

// ---------- quantize + transpose W: fp32 [K][N] -> int8 [N][K] ----------
__global__ void quant_wt_kernel(const float* __restrict__ w, int8_t* __restrict__ wt) {
    __shared__ int8_t t[64][65];
    const int k0 = blockIdx.y * 64;
    const int n0 = blockIdx.x * 64;
    const int tid = threadIdx.x;           // 256 threads
    const int rr = tid >> 4;               // 0..15
    const int c4 = (tid & 15) * 4;         // 0..60
    for (int p = 0; p < 4; ++p) {
        int r = rr + p * 16;
        float4 v = *(const float4*)&w[(size_t)(k0 + r) * NDIM + n0 + c4];
        t[c4 + 0][r] = (int8_t)rintf(v.x);
        t[c4 + 1][r] = (int8_t)rintf(v.y);
        t[c4 + 2][r] = (int8_t)rintf(v.z);
        t[c4 + 3][r] = (int8_t)rintf(v.w);
    }
    __syncthreads();
    for (int p = 0; p < 4; ++p) {
        int c = rr + p * 16;
        uint32_t o = (uint32_t)(uint8_t)t[c][c4 + 0]
                   | ((uint32_t)(uint8_t)t[c][c4 + 1] << 8)
                   | ((uint32_t)(uint8_t)t[c][c4 + 2] << 16)
                   | ((uint32_t)(uint8_t)t[c][c4 + 3] << 24);
        *(uint32_t*)&wt[(size_t)(n0 + c) * KDIM + k0 + c4] = o;
    }
}

// ---------- i8 GEMM: C = A * Bt^T + bias, int32 accum, BK=128, XOR-swizzled LDS ----------
// LDS layout: row-major [row][128B], 16B chunk c of row r stored at chunk (c ^ (r&7)).
// Staging (lane*16 linear) maps LDS slot (r, c) <- global chunk c ^ (r&7); since
// r&7 == (lane>>3)&7 per issue, the swizzle is a per-lane constant.
__global__ __launch_bounds__(256, 4)
void gemm_i8_kernel(const int8_t* __restrict__ A,   // [M][K] int8
                    const int8_t* __restrict__ Bt,  // [N][K] int8
                    const float* __restrict__ bias, // [N]
                    float* __restrict__ C) {        // [M][N] fp32
    __shared__ alignas(16) int8_t lA[BM * BK];  // 16 KB
    __shared__ alignas(16) int8_t lB[BN * BK];  // 16 KB

    const int tid  = threadIdx.x;
    const int lane = tid & 63;
    const int wave = tid >> 6;           // 0..3
    const int wm   = wave & 1;
    const int wn   = wave >> 1;
    const int m0   = blockIdx.y * BM;
    const int n0   = blockIdx.x * BN;

    // staging: wave covers rows [wave*32, +32) of each tile, 4 issues x (8 rows x 128B)
    const int srow = lane >> 3;                  // 0..7 row within issue
    const int schk = (lane & 7) ^ srow;          // swizzled source chunk
    const int8_t* gA = A  + (size_t)(m0 + wave * 32 + srow) * KDIM + schk * 16;
    const int8_t* gB = Bt + (size_t)(n0 + wave * 32 + srow) * KDIM + schk * 16;
    int8_t* lAw = &lA[wave * 4096];
    int8_t* lBw = &lB[wave * 4096];

    // fragments: A[m = lr][k = 16*(4s+quad) + j]; LDS chunk = (4s+quad) ^ (lr&7)
    const int quad = lane >> 4;
    const int lr   = lane & 15;
    const int sw   = lr & 7;
    const int arow = (wm * 64 + lr) * BK;
    const int brow = (wn * 64 + lr) * BK;

    v4i acc[4][4];
#pragma unroll
    for (int i = 0; i < 4; ++i)
#pragma unroll
        for (int j = 0; j < 4; ++j)
            acc[i][j] = (v4i){0, 0, 0, 0};

    for (int k0 = 0; k0 < KDIM; k0 += BK) {
        __syncthreads();                         // previous tile fully consumed
#pragma unroll
        for (int i = 0; i < 4; ++i) {
            async_ld16(gA + (size_t)i * 8 * KDIM, lAw + i * 1024);
            async_ld16(gB + (size_t)i * 8 * KDIM, lBw + i * 1024);
        }
        gA += BK; gB += BK;
        __syncthreads();                         // drains vmcnt -> tile visible

#pragma unroll
        for (int s = 0; s < 2; ++s) {
            const int cs = ((4 * s + quad) ^ sw) * 16;
            v4i af[4], bf[4];
#pragma unroll
            for (int i = 0; i < 4; ++i)
                af[i] = *(const v4i*)&lA[arow + i * 16 * BK + cs];
#pragma unroll
            for (int j = 0; j < 4; ++j)
                bf[j] = *(const v4i*)&lB[brow + j * 16 * BK + cs];
#pragma unroll
            for (int i = 0; i < 4; ++i)
#pragma unroll
                for (int j = 0; j < 4; ++j)
                    acc[i][j] = __builtin_amdgcn_mfma_i32_16x16x64_i8(af[i], bf[j], acc[i][j], 0, 0, 0);
        }
    }

    // epilogue: C/D layout col = lane&15, row = quad*4 + reg (verified, dtype-indep)
    const int crow = m0 + wm * 64 + quad * 4;
    const int ccol = n0 + wn * 64 + lr;
    float bj[4];
#pragma unroll
    for (int j = 0; j < 4; ++j) bj[j] = bias[ccol + j * 16];
#pragma unroll
    for (int i = 0; i < 4; ++i)
#pragma unroll
        for (int j = 0; j < 4; ++j)
#pragma unroll
            for (int r = 0; r < 4; ++r)
                C[(size_t)(crow + i * 16 + r) * NDIM + (ccol + j * 16)] = (float)acc[i][j][r] + bj[j];
}

extern "C" void kernel_launch(void* const* d_in, const int* in_sizes, int n_in,
                              void* d_out, int out_size, void* d_ws, size_t ws_size,
                              hipStream_t stream) {
    const float* x    = (const float*)d_in[0];   // [8192, 2048] fp32
    const float* w    = (const float*)d_in[1];   // [2048, 2048] fp32 (integer-valued)
    const float* xs   = (const float*)d_in[2];   // scalar
    const float* bias = (const float*)d_in[3];   // [2048]
    float* out = (float*)d_out;                  // [8192, 2048] fp32

    int8_t* xq = (int8_t*)d_ws;                          // 16 MB
    int8_t* wt = xq + (size_t)MDIM * KDIM;               //  4 MB

    // 16 bytes (int8) per thread
    quant_x_kernel<<<((size_t)MDIM * KDIM / 16) / 256, 256, 0, stream>>>(
        (const float4*)x, (uint4*)xq, xs);
    quant_wt_kernel<<<dim3(NDIM / 64, KDIM / 64), 256, 0, stream>>>(w, wt);
    gemm_i8_kernel<<<dim3(NDIM / BN, MDIM / BM), 256, 0, stream>>>(xq, wt, bias, out);
}

// Round 3
// 168.113 us; speedup vs baseline: 1.0306x; 1.0034x over previous
//
#include <hip/hip_runtime.h>
#include <cstdint>
#include <cstddef>

// Problem shape (fixed by setup_inputs): hidden [4,2048,2048] -> M=8192, K=2048, N=2048
#define MDIM 8192
#define NDIM 2048
#define KDIM 2048

constexpr int BM = 128, BN = 128, BK = 64;   // dbuf: 2 x (8KB A + 8KB B) = 32 KB LDS

typedef int v4i __attribute__((ext_vector_type(4)));

__device__ __forceinline__ void async_ld16(const void* g, void* l) {
    __builtin_amdgcn_global_load_lds(
        (const __attribute__((address_space(1))) int*)g,
        (__attribute__((address_space(3))) int*)l,
        16, 0, 0);
}

// ---------- quantize x: fp32 -> int8; lane-contiguous float4 loads, 4B packed stores ----------
__device__ __forceinline__ uint32_t q8(float x, float inv) {
    float q = fminf(fmaxf(rintf(x * inv), -127.f), 127.f);
    return (uint32_t)((int)q) & 0xffu;
}

__global__ void quant_x_kernel(const float4* __restrict__ x, uint32_t* __restrict__ xq,
                               const float* __restrict__ scale_p) {
    int i = blockIdx.x * blockDim.x + threadIdx.x;   // one float4 -> 4 int8
    float inv = 1.0f / fmaxf(scale_p[0], 1e-8f);
    float4 v = x[i];
    xq[i] = q8(v.x, inv) | (q8(v.y, inv) << 8) | (q8(v.z, inv) << 16) | (q8(v.w, inv) << 24);
}

// ---------- quantize + transpose W: fp32 [K][N] -> int8 [N][K], packed-uint32 LDS ----------
__global__ void quant_wt_kernel(const float* __restrict__ w, uint32_t* __restrict__ wt) {
    __shared__ uint32_t t[64][17];         // t[r][c4/4]: 4 int8 (consecutive n) packed
    const int k0 = blockIdx.y * 64;
    const int n0 = blockIdx.x * 64;
    const int tid = threadIdx.x;           // 256 threads
    const int rr  = tid >> 4;              // 0..15
    const int c4  = (tid & 15) * 4;        // 0..60
#pragma unroll
    for (int p = 0; p < 4; ++p) {
        int r = rr + p * 16;
        float4 v = *(const float4*)&w[(size_t)(k0 + r) * NDIM + n0 + c4];
        uint32_t pk = (uint32_t)((int)rintf(v.x) & 0xff)
                    | ((uint32_t)((int)rintf(v.y) & 0xff) << 8)
                    | ((uint32_t)((int)rintf(v.z) & 0xff) << 16)
                    | ((uint32_t)((int)rintf(v.w) & 0xff) << 24);
        t[r][c4 >> 2] = pk;
    }
    __syncthreads();
    // read side: thread owns column c = rr+p*16, rows c4..c4+3 -> one uint32 out
#pragma unroll
    for (int p = 0; p < 4; ++p) {
        int c = rr + p * 16;
        uint32_t o = 0;
#pragma unroll
        for (int j = 0; j < 4; ++j) {
            uint32_t b = (t[c4 + j][c >> 2] >> ((c & 3) * 8)) & 0xffu;
            o |= b << (j * 8);
        }
        wt[((size_t)(n0 + c) * KDIM + k0 + c4) >> 2] = o;
    }
}

// ---------- i8 GEMM: C = A * Bt^T + bias, int32 accum, BK=64 LDS double-buffer ----------
// LDS tile row = 64B = 4 x 16B chunks; chunk c of row r stored at c ^ ((r>>1)&3)
// (uniform 2-way bank aliasing = free; period-4 c^(r&3) would 4-way conflict since
//  a 64B row spans only half the 32 banks).
__global__ __launch_bounds__(256, 4)
void gemm_i8_kernel(const int8_t* __restrict__ A,   // [M][K] int8
                    const int8_t* __restrict__ Bt,  // [N][K] int8
                    const float* __restrict__ bias, // [N]
                    float* __restrict__ C) {        // [M][N] fp32
    __shared__ alignas(16) int8_t lA[2][BM * BK];   // 2 x 8 KB
    __shared__ alignas(16) int8_t lB[2][BN * BK];

    const int tid  = threadIdx.x;
    const int lane = tid & 63;
    const int wave = tid >> 6;           // 0..3
    const int wm   = wave & 1;
    const int wn   = wave >> 1;
    const int m0   = blockIdx.y * BM;
    const int n0   = blockIdx.x * BN;

    // staging: wave covers rows [wave*32, +32), 2 issues x (16 rows x 64B = 1KB)
    const int srow = lane >> 2;                       // 0..15
    const int schk = (lane & 3) ^ ((srow >> 1) & 3);  // swizzled source chunk
    const int8_t* gA = A  + (size_t)(m0 + wave * 32 + srow) * KDIM + schk * 16;
    const int8_t* gB = Bt + (size_t)(n0 + wave * 32 + srow) * KDIM + schk * 16;
    const int lwo = wave * 2048;

    // fragments: lane reads row (.. + lr), global chunk quad -> LDS chunk quad^((lr>>1)&3)
    const int quad = lane >> 4;
    const int lr   = lane & 15;
    const int fchk = (quad ^ ((lr >> 1) & 3)) * 16;
    const int aoff = (wm * 64 + lr) * BK + fchk;
    const int boff = (wn * 64 + lr) * BK + fchk;

    v4i acc[4][4];
#pragma unroll
    for (int i = 0; i < 4; ++i)
#pragma unroll
        for (int j = 0; j < 4; ++j)
            acc[i][j] = (v4i){0, 0, 0, 0};

#define STAGE(buf, kof)                                                        \
    do {                                                                       \
        async_ld16(gA + (kof), &lA[buf][lwo]);                                 \
        async_ld16(gA + (kof) + (size_t)16 * KDIM, &lA[buf][lwo + 1024]);      \
        async_ld16(gB + (kof), &lB[buf][lwo]);                                 \
        async_ld16(gB + (kof) + (size_t)16 * KDIM, &lB[buf][lwo + 1024]);      \
    } while (0)

#define COMPUTE(buf)                                                           \
    do {                                                                       \
        v4i af[4], bf[4];                                                      \
        _Pragma("unroll")                                                      \
        for (int i = 0; i < 4; ++i)                                            \
            af[i] = *(const v4i*)&lA[buf][aoff + i * 16 * BK];                 \
        _Pragma("unroll")                                                      \
        for (int j = 0; j < 4; ++j)                                            \
            bf[j] = *(const v4i*)&lB[buf][boff + j * 16 * BK];                 \
        _Pragma("unroll")                                                      \
        for (int i = 0; i < 4; ++i)                                            \
            _Pragma("unroll")                                                  \
            for (int j = 0; j < 4; ++j)                                        \
                acc[i][j] = __builtin_amdgcn_mfma_i32_16x16x64_i8(             \
                    af[i], bf[j], acc[i][j], 0, 0, 0);                         \
    } while (0)

    STAGE(0, 0);
    int kof = BK;
    for (int it = 0; it < KDIM / BK - 1; ++it) {
        __syncthreads();                 // drains vmcnt: tile `it` visible; buf (it+1)&1 free
        STAGE((it + 1) & 1, kof);        // prefetch next tile (flies during compute)
        kof += BK;
        COMPUTE(it & 1);
    }
    __syncthreads();
    COMPUTE((KDIM / BK - 1) & 1);

    // epilogue: C/D layout col = lane&15, row = quad*4 + reg (verified, dtype-indep)
    const int crow = m0 + wm * 64 + quad * 4;
    const int ccol = n0 + wn * 64 + lr;
    float bj[4];
#pragma unroll
    for (int j = 0; j < 4; ++j) bj[j] = bias[ccol + j * 16];
#pragma unroll
    for (int i = 0; i < 4; ++i)
#pragma unroll
        for (int j = 0; j < 4; ++j)
#pragma unroll
            for (int r = 0; r < 4; ++r)
                C[(size_t)(crow + i * 16 + r) * NDIM + (ccol + j * 16)] = (float)acc[i][j][r] + bj[j];
}

extern "C" void kernel_launch(void* const* d_in, const int* in_sizes, int n_in,
                              void* d_out, int out_size, void* d_ws, size_t ws_size,
                              hipStream_t stream) {
    const float* x    = (const float*)d_in[0];   // [8192, 2048] fp32
    const float* w    = (const float*)d_in[1];   // [2048, 2048] fp32 (integer-valued)
    const float* xs   = (const float*)d_in[2];   // scalar
    const float* bias = (const float*)d_in[3];   // [2048]
    float* out = (float*)d_out;                  // [8192, 2048] fp32

    int8_t* xq = (int8_t*)d_ws;                          // 16 MB
    int8_t* wt = xq + (size_t)MDIM * KDIM;               //  4 MB

    quant_x_kernel<<<((size_t)MDIM * KDIM / 4) / 256, 256, 0, stream>>>(
        (const float4*)x, (uint32_t*)xq, xs);
    quant_wt_kernel<<<dim3(NDIM / 64, KDIM / 64), 256, 0, stream>>>(w, (uint32_t*)wt);
    gemm_i8_kernel<<<dim3(NDIM / BN, MDIM / BM), 256, 0, stream>>>(xq, wt, bias, out);
}